// Round 14
// baseline (524.058 us; speedup 1.0000x reference)
//
#include <hip/hip_runtime.h>
#include <math.h>

#define NN 50000
#define NREL 400
#define NLAYERS 3

static __device__ __forceinline__ float clip15(float x) { return fminf(fmaxf(x, -15.f), 15.f); }

// bf16 RNE split helpers (bit-level; agg_k's f1 split must match wconv_k's W split style)
static __device__ __forceinline__ unsigned short f2bf(float f) {
  unsigned u = __float_as_uint(f);
  unsigned r = (u + 0x7FFFu + ((u >> 16) & 1u)) >> 16;
  return (unsigned short)r;
}
static __device__ __forceinline__ float bf2f(unsigned short s) {
  return __uint_as_float(((unsigned)s) << 16);
}

typedef __attribute__((ext_vector_type(8))) short bf16x8;
typedef __attribute__((ext_vector_type(4))) float f32x4;

// ---------------- CSR build ----------------
__global__ void count_k(const int* __restrict__ dst, int* __restrict__ deg, int E) {
  int e = blockIdx.x * blockDim.x + threadIdx.x;
  if (e < E) atomicAdd(&deg[dst[e]], 1);
}

__global__ void scan_k(const int* __restrict__ deg, int* __restrict__ start, int* __restrict__ cursor,
                       int* __restrict__ counter, float* __restrict__ logsum, int N) {
  int n = blockIdx.x * blockDim.x + threadIdx.x;
  int lane = threadIdx.x & 63;
  int d = (n < N) ? deg[n] : 0;
  int pre = d;
  #pragma unroll
  for (int off = 1; off < 64; off <<= 1) { int t = __shfl_up(pre, off); if (lane >= off) pre += t; }
  int base = 0;
  if (lane == 63) base = atomicAdd(counter, pre);
  base = __shfl(base, 63);
  if (n < N) { int pos = base + pre - d; start[n] = pos; cursor[n] = pos; }
  float v = (n < N) ? logf((float)d + 1.0f) : 0.f;
  #pragma unroll
  for (int off = 32; off; off >>= 1) v += __shfl_xor(v, off);
  if (lane == 0) atomicAdd(logsum, v);
}

__global__ void scale_k(const int* __restrict__ deg, const float* __restrict__ logsum,
                        float* __restrict__ scale, int N) {
  int n = blockIdx.x * blockDim.x + threadIdx.x;
  if (n < N) scale[n] = logf((float)deg[n] + 1.0f) * (float)N / logsum[0];
}

__global__ void scatter_k(const int* __restrict__ src, const int* __restrict__ dst,
                          const int* __restrict__ typ, int* __restrict__ cursor,
                          int2* __restrict__ csr, int E) {
  int e = blockIdx.x * blockDim.x + threadIdx.x;
  if (e < E) {
    int dd = dst[e];
    int pos = atomicAdd(&cursor[dd], 1);
    csr[pos] = make_int2(src[e], typ[e]);
  }
}

// ---------------- W pre-convert: aggW [3][512][64] f32 -> WT [3][4][64][256] bf16 ----------------
// part 0 = Wa_hi, 1 = Wa_lo (k 0..255); 2 = Wb_hi, 3 = Wb_lo (k 256..511). Layout [out][k].
__global__ void wconv_k(const float* __restrict__ aggW, unsigned short* __restrict__ WT) {
  int idx = blockIdx.x * blockDim.x + threadIdx.x;   // over 3*64*256
  if (idx >= 3 * 64 * 256) return;
  int k = idx & 255;
  int out = (idx >> 8) & 63;
  int l = idx >> 14;
  const float* Wl = aggW + (size_t)l * 512 * 64;
  float wa = Wl[(size_t)k * 64 + out];
  float wb = Wl[(size_t)(256 + k) * 64 + out];
  unsigned short wah = f2bf(wa);
  unsigned short wal = f2bf(wa - bf2f(wah));
  unsigned short wbh = f2bf(wb);
  unsigned short wbl = f2bf(wb - bf2f(wbh));
  unsigned short* WTl = WT + (size_t)l * 4 * 64 * 256;
  WTl[((size_t)0 * 64 + out) * 256 + k] = wah;
  WTl[((size_t)1 * 64 + out) * 256 + k] = wal;
  WTl[((size_t)2 * 64 + out) * 256 + k] = wbh;
  WTl[((size_t)3 * 64 + out) * 256 + k] = wbl;
}

// ---------------- init ----------------
// scalars layout: [0..63]=c_q (lin_b + q @ lin_W[64:128]) ; [64]=zero_s ; [65]=head_s
__global__ void prep_k(const float* __restrict__ head_embeds, const float* __restrict__ rel_table,
                       const float* __restrict__ lin_W, const float* __restrict__ lin_b,
                       const float* __restrict__ mlp_W1, const float* __restrict__ mlp_b1,
                       const float* __restrict__ mlp_W2, const float* __restrict__ mlp_b2,
                       const int* __restrict__ head_index, const int* __restrict__ r_index,
                       float* __restrict__ hidden, float* __restrict__ scalars) {
  int j = threadIdx.x;  // 0..63
  int r = r_index[0], hd = head_index[0];
  float qj = rel_table[r * 64 + j];
  float cq = lin_b[j];
  for (int k = 0; k < 64; ++k) cq += __shfl(qj, k) * lin_W[(64 + k) * 64 + j];
  scalars[j] = cq;
  float t = fmaxf(mlp_b1[j], 0.f) * mlp_W2[j] + fmaxf(mlp_b1[64 + j], 0.f) * mlp_W2[64 + j];
  #pragma unroll
  for (int off = 32; off; off >>= 1) t += __shfl_xor(t, off);
  float zs = clip15(t + mlp_b2[0]);
  float hj = head_embeds[j];
  hidden[(size_t)hd * 64 + j] = hj;
  float heur = cq;
  for (int k = 0; k < 64; ++k) heur += __shfl(hj, k) * lin_W[k * 64 + j];
  float xj = hj * heur;
  float h1a = mlp_b1[j], h1b = mlp_b1[64 + j];
  for (int k = 0; k < 64; ++k) {
    float xk = __shfl(xj, k);
    h1a += xk * mlp_W1[k * 128 + j];
    h1b += xk * mlp_W1[k * 128 + 64 + j];
  }
  h1a = fmaxf(h1a, 0.f); h1b = fmaxf(h1b, 0.f);
  float p = h1a * mlp_W2[j] + h1b * mlp_W2[64 + j];
  #pragma unroll
  for (int off = 32; off; off >>= 1) p += __shfl_xor(p, off);
  float hs = clip15(p + mlp_b2[0]);
  if (j == 0) { scalars[64] = zs; scalars[65] = hs; }
}

__global__ void fill_k(float* __restrict__ score, const float* __restrict__ scalars,
                       const int* __restrict__ head_index, int N) {
  int n = blockIdx.x * blockDim.x + threadIdx.x;
  if (n < N) score[n] = (n == head_index[0]) ? scalars[65] : scalars[64];
}

// ---------------- per-layer ----------------
// per-node gate precompute (one sigmoid per node, not per edge — r11 lesson)
__global__ void gsig_k(const float* __restrict__ score, float* __restrict__ gate, int N) {
  int n = blockIdx.x * blockDim.x + threadIdx.x;
  if (n < N) gate[n] = 1.f / (1.f + expf(-score[n]));
}

// one wave per node; lane = dim; 8-wide edge unroll. Reads hidden + broadcast gate[src]
// (li = g*h identical arithmetic to the old gate_k path -> bitwise-same stats).
// Emits f1 as SPLIT bf16 hi/lo planes (same split gemm_k used internally in r13 ->
// bitwise-identical gemm result, but the conversion cost moves into this latency-bound kernel).
__global__ __launch_bounds__(256) void agg_k(const float* __restrict__ hidden, const float* __restrict__ gate,
                                             const int2* __restrict__ csr,
                                             const int* __restrict__ start, const int* __restrict__ deg,
                                             const float* __restrict__ relW,
                                             unsigned short* __restrict__ f1h, unsigned short* __restrict__ f1l,
                                             int N) {
  int wid = threadIdx.x >> 6;
  int lane = threadIdx.x & 63;
  int node = blockIdx.x * 4 + wid;
  if (node >= N) return;
  int base = start[node], d = deg[node];
  float sum = 0.f, sq = 0.f, mx = -3.402823e38f, mn = 3.402823e38f;
  int e = 0;
  for (; e + 8 <= d; e += 8) {
    int2 p[8];
    #pragma unroll
    for (int i = 0; i < 8; ++i) p[i] = csr[base + e + i];
    float m[8];
    #pragma unroll
    for (int i = 0; i < 8; ++i) {
      float li = gate[p[i].x] * hidden[p[i].x * 64 + lane];
      float w = relW[p[i].y * 64 + lane];
      m[i] = li * w;
    }
    #pragma unroll
    for (int i = 0; i < 8; ++i) {
      sum += m[i]; sq += m[i] * m[i];
      mx = fmaxf(mx, m[i]); mn = fminf(mn, m[i]);
    }
  }
  for (; e + 4 <= d; e += 4) {
    int2 p0 = csr[base + e], p1 = csr[base + e + 1];
    int2 p2 = csr[base + e + 2], p3 = csr[base + e + 3];
    float a0 = gate[p0.x] * hidden[p0.x * 64 + lane], w0 = relW[p0.y * 64 + lane];
    float a1 = gate[p1.x] * hidden[p1.x * 64 + lane], w1 = relW[p1.y * 64 + lane];
    float a2 = gate[p2.x] * hidden[p2.x * 64 + lane], w2 = relW[p2.y * 64 + lane];
    float a3 = gate[p3.x] * hidden[p3.x * 64 + lane], w3 = relW[p3.y * 64 + lane];
    float m0 = a0 * w0, m1 = a1 * w1, m2 = a2 * w2, m3 = a3 * w3;
    sum += (m0 + m1) + (m2 + m3);
    sq += (m0 * m0 + m1 * m1) + (m2 * m2 + m3 * m3);
    mx = fmaxf(fmaxf(mx, fmaxf(m0, m1)), fmaxf(m2, m3));
    mn = fminf(fminf(mn, fminf(m0, m1)), fminf(m2, m3));
  }
  for (; e < d; ++e) {
    int2 p = csr[base + e];
    float li = gate[p.x] * hidden[p.x * 64 + lane];
    float m = li * relW[p.y * 64 + lane];
    sum += m; sq += m * m; mx = fmaxf(mx, m); mn = fminf(mn, m);
  }
  unsigned short* oh = f1h + (size_t)node * 256;
  unsigned short* ol = f1l + (size_t)node * 256;
  float v0, v1, v2, v3;
  if (d > 0) {
    float inv = 1.0f / (float)d;
    float mean = sum * inv, sqm = sq * inv;
    float sd = sqrtf(fmaxf(sqm - mean * mean, 0.f) + 1e-6f);
    v0 = mean; v1 = mx; v2 = mn; v3 = sd;
  } else {
    v0 = 0.f; v1 = 0.f; v2 = 0.f; v3 = 0.f;
  }
  unsigned short h0 = f2bf(v0), h1 = f2bf(v1), h2 = f2bf(v2), h3 = f2bf(v3);
  oh[lane] = h0;        ol[lane] = f2bf(v0 - bf2f(h0));
  oh[64 + lane] = h1;   ol[64 + lane] = f2bf(v1 - bf2f(h1));
  oh[128 + lane] = h2;  ol[128 + lane] = f2bf(v2 - bf2f(h2));
  oh[192 + lane] = h3;  ol[192 + lane] = f2bf(v3 - bf2f(h3));
}

// update = f1 @ Wa + scale*(f1 @ Wb) + b ; hidden += update (deg>0)
// MFMA bf16-split; A arrives pre-split (f1h/f1l) -> staging is pure uint4 copies.
#define KP 40
__global__ __launch_bounds__(256) void gemm_k(const unsigned short* __restrict__ f1h,
                                              const unsigned short* __restrict__ f1l,
                                              const unsigned short* __restrict__ WT,
                                              const float* __restrict__ aggb, const float* __restrict__ scale,
                                              const int* __restrict__ deg, float* __restrict__ hidden, int N) {
  __shared__ __align__(16) unsigned short sA[2][64 * KP];  // hi, lo
  __shared__ __align__(16) unsigned short sW[4][64 * KP];  // Wa_hi, Wa_lo, Wb_hi, Wb_lo
  int tid = threadIdx.x;
  int wv = tid >> 6;        // wave -> node stripe (16 rows)
  int l = tid & 63;
  int lrow = l & 15;
  int lhi = l >> 4;         // 0..3
  int n0 = blockIdx.x * 64;

  f32x4 acc[8];
  #pragma unroll
  for (int i = 0; i < 8; ++i) acc[i] = (f32x4){0.f, 0.f, 0.f, 0.f};

  int anode = tid >> 2;            // 0..63
  int akq = (tid & 3) * 8;         // k offset within chunk (8 elements)
  bool avalid = (n0 + anode) < N;
  const unsigned short* Ah = f1h + (size_t)(n0 + anode) * 256 + akq;
  const unsigned short* Al = f1l + (size_t)(n0 + anode) * 256 + akq;

  for (int kc = 0; kc < 8; ++kc) {
    uint4 vh = make_uint4(0, 0, 0, 0), vl = vh;
    if (avalid) {
      vh = *(const uint4*)(Ah + kc * 32);
      vl = *(const uint4*)(Al + kc * 32);
    }
    *(uint4*)&sA[0][anode * KP + akq] = vh;
    *(uint4*)&sA[1][anode * KP + akq] = vl;
    {
      int wrow = tid >> 2;
      int wkq = (tid & 3) * 8;
      #pragma unroll
      for (int p = 0; p < 4; ++p) {
        const unsigned short* src = WT + ((size_t)p * 64 + wrow) * 256 + kc * 32 + wkq;
        *(uint4*)&sW[p][wrow * KP + wkq] = *(const uint4*)src;
      }
    }
    __syncthreads();
    {
      int arow = (wv * 16 + lrow) * KP + lhi * 8;
      bf16x8 ah = *(const bf16x8*)&sA[0][arow];
      bf16x8 al = *(const bf16x8*)&sA[1][arow];
      #pragma unroll
      for (int t = 0; t < 4; ++t) {
        int wr = (t * 16 + lrow) * KP + lhi * 8;
        bf16x8 wah = *(const bf16x8*)&sW[0][wr];
        bf16x8 wal = *(const bf16x8*)&sW[1][wr];
        acc[t] = __builtin_amdgcn_mfma_f32_16x16x32_bf16(ah, wah, acc[t], 0, 0, 0);
        acc[t] = __builtin_amdgcn_mfma_f32_16x16x32_bf16(ah, wal, acc[t], 0, 0, 0);
        acc[t] = __builtin_amdgcn_mfma_f32_16x16x32_bf16(al, wah, acc[t], 0, 0, 0);
        bf16x8 wbh = *(const bf16x8*)&sW[2][wr];
        bf16x8 wbl = *(const bf16x8*)&sW[3][wr];
        acc[4 + t] = __builtin_amdgcn_mfma_f32_16x16x32_bf16(ah, wbh, acc[4 + t], 0, 0, 0);
        acc[4 + t] = __builtin_amdgcn_mfma_f32_16x16x32_bf16(ah, wbl, acc[4 + t], 0, 0, 0);
        acc[4 + t] = __builtin_amdgcn_mfma_f32_16x16x32_bf16(al, wbh, acc[4 + t], 0, 0, 0);
      }
    }
    __syncthreads();
  }

  // epilogue: C/D layout col=lane&15, row=(lane>>4)*4+reg  [m89 verified]
  #pragma unroll
  for (int r = 0; r < 4; ++r) {
    int node = n0 + wv * 16 + lhi * 4 + r;
    if (node < N && deg[node] > 0) {
      float sc = scale[node];
      #pragma unroll
      for (int t = 0; t < 4; ++t) {
        int out = t * 16 + lrow;
        float* hp = &hidden[(size_t)node * 64 + out];
        *hp += acc[t][r] + sc * acc[4 + t][r] + aggb[out];
      }
    }
  }
}

// ---------------- score: register-blocked tile kernel ----------------
#define SC_LDS 12992
__global__ __launch_bounds__(256) void score2_k(const float* __restrict__ hidden, float* __restrict__ score,
                                                const int* __restrict__ deg, const float* __restrict__ lin_W,
                                                const float* __restrict__ mlp_W1, const float* __restrict__ mlp_b1,
                                                const float* __restrict__ mlp_W2, const float* __restrict__ mlp_b2,
                                                const float* __restrict__ scalars, int N) {
  __shared__ float smem[SC_LDS];
  float* X   = smem;
  float* H   = smem + 4160;
  float* WA  = smem + 8320;
  float* W1s = smem + 4160;
  float* sW2 = smem + 12416;
  float* sb1 = smem + 12544;
  float* scq = smem + 12672;
  float* pred= smem + 12736;

  int t = threadIdx.x;
  int lane = t & 63;
  int g = t >> 6;
  int n0 = blockIdx.x * 64;

  for (int i = t; i < 1024; i += 256) ((float4*)WA)[i] = ((const float4*)lin_W)[i];
  if (t < 128) { sW2[t] = mlp_W2[t]; sb1[t] = mlp_b1[t]; }
  if (t < 64) scq[t] = scalars[t];
  for (int i = t; i < 1024; i += 256) {
    int node = i >> 4;
    int k4 = (i & 15) << 2;
    float4 v = make_float4(0.f, 0.f, 0.f, 0.f);
    if (n0 + node < N) v = ((const float4*)(hidden + (size_t)(n0 + node) * 64))[i & 15];
    float* hp = &H[node * 65 + k4];
    hp[0] = v.x; hp[1] = v.y; hp[2] = v.z; hp[3] = v.w;
  }
  __syncthreads();

  float acc[16];
  #pragma unroll
  for (int i = 0; i < 16; ++i) acc[i] = scq[g * 16 + i];
  #pragma unroll 8
  for (int kk = 0; kk < 64; ++kk) {
    float h = H[lane * 65 + kk];
    const float4* wr = (const float4*)&WA[kk * 64 + g * 16];
    float4 w0 = wr[0], w1 = wr[1], w2 = wr[2], w3 = wr[3];
    acc[0]  += h * w0.x; acc[1]  += h * w0.y; acc[2]  += h * w0.z; acc[3]  += h * w0.w;
    acc[4]  += h * w1.x; acc[5]  += h * w1.y; acc[6]  += h * w1.z; acc[7]  += h * w1.w;
    acc[8]  += h * w2.x; acc[9]  += h * w2.y; acc[10] += h * w2.z; acc[11] += h * w2.w;
    acc[12] += h * w3.x; acc[13] += h * w3.y; acc[14] += h * w3.z; acc[15] += h * w3.w;
  }
  #pragma unroll
  for (int i = 0; i < 16; ++i) {
    int j = g * 16 + i;
    X[lane * 65 + j] = H[lane * 65 + j] * acc[i];
  }
  __syncthreads();

  for (int i = t; i < 2048; i += 256) ((float4*)W1s)[i] = ((const float4*)mlp_W1)[i];
  __syncthreads();

  float acc2[32];
  #pragma unroll
  for (int i = 0; i < 32; ++i) acc2[i] = sb1[g * 32 + i];
  #pragma unroll 4
  for (int kk = 0; kk < 64; ++kk) {
    float xv = X[lane * 65 + kk];
    const float4* wr = (const float4*)&W1s[kk * 128 + g * 32];
    #pragma unroll
    for (int s = 0; s < 8; ++s) {
      float4 w = wr[s];
      acc2[s * 4 + 0] += xv * w.x; acc2[s * 4 + 1] += xv * w.y;
      acc2[s * 4 + 2] += xv * w.z; acc2[s * 4 + 3] += xv * w.w;
    }
  }
  float p = 0.f;
  #pragma unroll
  for (int i = 0; i < 32; ++i) p += fmaxf(acc2[i], 0.f) * sW2[g * 32 + i];
  pred[g * 64 + lane] = p;
  __syncthreads();
  if (t < 64) {
    int node = n0 + t;
    if (node < N && deg[node] > 0)
      score[node] = pred[t] + pred[64 + t] + pred[128 + t] + pred[192 + t] + mlp_b2[0];
  }
}

__global__ void out_k(const float* __restrict__ score, const int* __restrict__ t_index,
                      float* __restrict__ out, int T) {
  int i = blockIdx.x * blockDim.x + threadIdx.x;
  if (i < T) out[i] = score[t_index[i]];
}

// ---------------- launch ----------------
extern "C" void kernel_launch(void* const* d_in, const int* in_sizes, int n_in,
                              void* d_out, int out_size, void* d_ws, size_t ws_size,
                              hipStream_t stream) {
  const float* head_embeds = (const float*)d_in[0];
  const float* rel_table   = (const float*)d_in[1];
  const float* rel_W       = (const float*)d_in[2];
  const float* agg_W       = (const float*)d_in[3];
  const float* agg_b       = (const float*)d_in[4];
  const float* lin_W       = (const float*)d_in[5];
  const float* lin_b       = (const float*)d_in[6];
  const float* mlp_W1      = (const float*)d_in[7];
  const float* mlp_b1      = (const float*)d_in[8];
  const float* mlp_W2      = (const float*)d_in[9];
  const float* mlp_b2      = (const float*)d_in[10];
  const int* edge_src      = (const int*)d_in[11];
  const int* edge_dst      = (const int*)d_in[12];
  const int* edge_type     = (const int*)d_in[13];
  const int* head_index    = (const int*)d_in[14];
  const int* r_index       = (const int*)d_in[15];
  const int* t_index       = (const int*)d_in[16];
  int E = in_sizes[11];
  int T = in_sizes[16];
  int N = NN;

  char* w = (char*)d_ws;
  size_t off = 0;
  auto alloc = [&](size_t bytes) {
    void* p = w + off;
    off = (off + bytes + 255) & ~(size_t)255;
    return p;
  };
  int* deg      = (int*)alloc((size_t)N * 4);
  int* start    = (int*)alloc((size_t)N * 4);
  int* cursor   = (int*)alloc((size_t)N * 4);
  float* scale  = (float*)alloc((size_t)N * 4);
  int* counter  = (int*)alloc(4);
  float* logsum = (float*)alloc(4);
  float* scalars= (float*)alloc(66 * 4);
  int2* csr     = (int2*)alloc((size_t)E * 8);
  float* hidden = (float*)alloc((size_t)N * 64 * 4);
  float* score  = (float*)alloc((size_t)N * 4);
  float* gate   = (float*)alloc((size_t)N * 4);
  unsigned short* f1h = (unsigned short*)alloc((size_t)N * 256 * 2);
  unsigned short* f1l = (unsigned short*)alloc((size_t)N * 256 * 2);
  unsigned short* WT = (unsigned short*)alloc((size_t)3 * 4 * 64 * 256 * 2);
  if (off > ws_size) return;  // workspace too small -> fail loudly via wrong output

  hipMemsetAsync(deg, 0, (size_t)N * 4, stream);
  hipMemsetAsync(counter, 0, 4, stream);
  hipMemsetAsync(logsum, 0, 4, stream);
  hipMemsetAsync(hidden, 0, (size_t)N * 64 * 4, stream);

  count_k<<<(E + 255) / 256, 256, 0, stream>>>(edge_dst, deg, E);
  scan_k<<<(N + 255) / 256, 256, 0, stream>>>(deg, start, cursor, counter, logsum, N);
  scale_k<<<(N + 255) / 256, 256, 0, stream>>>(deg, logsum, scale, N);
  scatter_k<<<(E + 255) / 256, 256, 0, stream>>>(edge_src, edge_dst, edge_type, cursor, csr, E);
  wconv_k<<<(3 * 64 * 256 + 255) / 256, 256, 0, stream>>>(agg_W, WT);
  prep_k<<<1, 64, 0, stream>>>(head_embeds, rel_table, lin_W, lin_b, mlp_W1, mlp_b1, mlp_W2, mlp_b2,
                               head_index, r_index, hidden, scalars);
  fill_k<<<(N + 255) / 256, 256, 0, stream>>>(score, scalars, head_index, N);

  for (int l = 0; l < NLAYERS; ++l) {
    gsig_k<<<(N + 255) / 256, 256, 0, stream>>>(score, gate, N);
    agg_k<<<(N + 3) / 4, 256, 0, stream>>>(hidden, gate, csr, start, deg,
                                           rel_W + (size_t)l * NREL * 64, f1h, f1l, N);
    gemm_k<<<(N + 63) / 64, 256, 0, stream>>>(f1h, f1l, WT + (size_t)l * 4 * 64 * 256,
                                              agg_b + (size_t)l * 64, scale, deg, hidden, N);
    score2_k<<<(N + 63) / 64, 256, 0, stream>>>(hidden, score, deg, lin_W, mlp_W1, mlp_b1, mlp_W2, mlp_b2,
                                                scalars, N);
  }
  out_k<<<(T + 255) / 256, 256, 0, stream>>>(score, t_index, (float*)d_out, T);
}